// Round 1
// baseline (868.370 us; speedup 1.0000x reference)
//
#include <hip/hip_runtime.h>
#include <stdint.h>

#define T_TOK 16384
#define DIM 512
#define HID 2048
#define NE 16
#define TOPK 4
#define BM 128
#define BN 128
#define BK 64
#define PAIR_CAP 67584      // 65536 + 16*128 padding
#define MAX_TILES 528       // PAIR_CAP / BM
#define NB_CNT 64

typedef short s8v __attribute__((ext_vector_type(8)));
typedef float f4v __attribute__((ext_vector_type(4)));
typedef unsigned int u4v __attribute__((ext_vector_type(4)));

__device__ __forceinline__ unsigned short f2bf(float f) {
  unsigned int u = __builtin_bit_cast(unsigned int, f);
  u = (u + 0x7fffu + ((u >> 16) & 1u)) >> 16;
  return (unsigned short)u;
}

// ---------------- precast kernels ----------------
__global__ __launch_bounds__(256) void k_cast_x(const float* __restrict__ x,
                                                unsigned short* __restrict__ xb) {
  int i = (blockIdx.x * 256 + threadIdx.x) * 4;
  float4 v = *(const float4*)(x + i);
  ushort4 o;
  o.x = f2bf(v.x); o.y = f2bf(v.y); o.z = f2bf(v.z); o.w = f2bf(v.w);
  *(ushort4*)(xb + i) = o;
}

// src [z][R][C] fp32 -> dst [z][C][R] bf16
__global__ __launch_bounds__(256) void k_transpose_cast(const float* __restrict__ src,
                                                        unsigned short* __restrict__ dst,
                                                        int R, int C) {
  __shared__ float tile[32][33];
  size_t zo = (size_t)blockIdx.z * R * C;
  src += zo; dst += zo;
  int c0 = blockIdx.x * 32, r0 = blockIdx.y * 32;
  int tx = threadIdx.x, ty = threadIdx.y;
#pragma unroll
  for (int i = 0; i < 4; ++i)
    tile[ty + 8 * i][tx] = src[(size_t)(r0 + ty + 8 * i) * C + c0 + tx];
  __syncthreads();
#pragma unroll
  for (int i = 0; i < 4; ++i)
    dst[(size_t)(c0 + ty + 8 * i) * R + r0 + tx] = f2bf(tile[tx][ty + 8 * i]);
}

// ---------------- routing ----------------
__global__ __launch_bounds__(256) void k_router(const float* __restrict__ x,
                                                const float* __restrict__ rw,
                                                const float* __restrict__ rb,
                                                int* __restrict__ topki,
                                                float* __restrict__ topkg) {
  int wv = threadIdx.x >> 6, lane = threadIdx.x & 63;
  int t = blockIdx.x * 4 + wv;
  const float* xr = x + (size_t)t * DIM;
  double acc[NE];
#pragma unroll
  for (int e = 0; e < NE; ++e) acc[e] = 0.0;
  for (int it = 0; it < DIM / 64; ++it) {
    float xv = xr[it * 64 + lane];
    const float* r = rw + (size_t)(it * 64 + lane) * NE;
#pragma unroll
    for (int e = 0; e < NE; ++e) acc[e] += (double)xv * (double)r[e];
  }
#pragma unroll
  for (int off = 32; off >= 1; off >>= 1) {
#pragma unroll
    for (int e = 0; e < NE; ++e) acc[e] += __shfl_xor(acc[e], off, 64);
  }
  if (lane == 0) {
    float v[NE];
#pragma unroll
    for (int e = 0; e < NE; ++e) v[e] = (float)acc[e] + rb[e];
    int idx[TOPK]; float val[TOPK];
#pragma unroll
    for (int k = 0; k < TOPK; ++k) {
      float best = -1e30f; int bi = 0;
#pragma unroll
      for (int e = 0; e < NE; ++e)
        if (v[e] > best) { best = v[e]; bi = e; }
      idx[k] = bi; val[k] = best; v[bi] = -1e30f;
    }
    float m = val[0], s = 0.f, g[TOPK];
#pragma unroll
    for (int k = 0; k < TOPK; ++k) { g[k] = __expf(val[k] - m); s += g[k]; }
    float inv = 1.f / s;
#pragma unroll
    for (int k = 0; k < TOPK; ++k) {
      topki[t * TOPK + k] = idx[k];
      topkg[t * TOPK + k] = g[k] * inv;
    }
  }
}

// meta layout (ints): [0]=tiles_total, [1..17]=padded offsets po[0..16],
// [32..1055]=blockbase[64][16], [1056..2079]=hist[64][16]
__global__ __launch_bounds__(256) void k_count(const int* __restrict__ topki,
                                               int* __restrict__ meta) {
  __shared__ int lcnt[NE];
  int tid = threadIdx.x;
  if (tid < NE) lcnt[tid] = 0;
  __syncthreads();
  int base = blockIdx.x * 1024 + tid * 4;
#pragma unroll
  for (int j = 0; j < 4; ++j) atomicAdd(&lcnt[topki[base + j]], 1);
  __syncthreads();
  if (tid < NE) meta[1056 + blockIdx.x * NE + tid] = lcnt[tid];
}

__global__ __launch_bounds__(256) void k_plan(int* __restrict__ meta,
                                              int* __restrict__ ptok,
                                              float* __restrict__ pgate) {
  __shared__ int cnt_s[NE], po_s[NE + 1];
  int tid = threadIdx.x;
  if (tid < NE) {
    int s = 0;
    for (int b = 0; b < NB_CNT; ++b) s += meta[1056 + b * NE + tid];
    cnt_s[tid] = s;
  }
  __syncthreads();
  if (tid == 0) {
    int off = 0;
    for (int e = 0; e < NE; ++e) {
      po_s[e] = off;
      meta[1 + e] = off;
      off += ((cnt_s[e] + BM - 1) / BM) * BM;
    }
    po_s[NE] = off;
    meta[1 + NE] = off;
    meta[0] = off / BM;
  }
  __syncthreads();
  if (tid < NE) {
    int run = po_s[tid];
    for (int b = 0; b < NB_CNT; ++b) {
      meta[32 + b * NE + tid] = run;
      run += meta[1056 + b * NE + tid];
    }
  }
  for (int e = 0; e < NE; ++e) {
    int start = po_s[e] + cnt_s[e], end = po_s[e + 1];
    for (int i = start + tid; i < end; i += 256) { ptok[i] = 0; pgate[i] = 0.f; }
  }
}

__global__ __launch_bounds__(256) void k_scatter(const int* __restrict__ topki,
                                                 const float* __restrict__ topkg,
                                                 const int* __restrict__ meta,
                                                 int* __restrict__ ptok,
                                                 float* __restrict__ pgate) {
  __shared__ int lcnt[NE];
  int tid = threadIdx.x;
  if (tid < NE) lcnt[tid] = 0;
  __syncthreads();
  int base = blockIdx.x * 1024 + tid * 4;
#pragma unroll
  for (int j = 0; j < 4; ++j) {
    int i = base + j;
    int e = topki[i];
    int r = atomicAdd(&lcnt[e], 1);
    int slot = meta[32 + blockIdx.x * NE + e] + r;
    ptok[slot] = i >> 2;
    pgate[slot] = topkg[i];
  }
}

// ---------------- GEMM1: h = relu(X[pairs] @ W1[e] + b1[e]) ----------------
__global__ __launch_bounds__(256) void k_gemm1(const unsigned short* __restrict__ xb,
                                               const unsigned short* __restrict__ w1t,
                                               const float* __restrict__ b1,
                                               const int* __restrict__ ptok,
                                               const int* __restrict__ meta,
                                               unsigned short* __restrict__ hbuf,
                                               int chunk_start) {
  int tile = chunk_start + blockIdx.x;
  if (tile >= meta[0]) return;
  int row0 = tile * BM;
  int e = 0;
#pragma unroll
  for (int i = 1; i < NE; ++i)
    if (row0 >= meta[1 + i]) e = i;
  int nblock = blockIdx.y * BN;
  __shared__ __align__(16) unsigned short Al[BM * BK];
  __shared__ __align__(16) unsigned short Bl[BN * BK];
  int tid = threadIdx.x;
  int lane = tid & 63, w = tid >> 6;
  int wm = w >> 1, wn = w & 1;
  int srow = tid >> 3;
  int scol = (tid & 7) * 8;
  const unsigned short* asrc[4];
#pragma unroll
  for (int r = 0; r < 4; ++r)
    asrc[r] = xb + (size_t)ptok[row0 + r * 32 + srow] * DIM + scol;
  const unsigned short* bsrc = w1t + ((size_t)e * HID + nblock + srow) * DIM + scol;
  f4v acc[4][4] = {};
  int lrow = lane & 15, lquad = lane >> 4;
  for (int k0 = 0; k0 < DIM; k0 += BK) {
#pragma unroll
    for (int r = 0; r < 4; ++r)
      *(u4v*)&Al[(r * 32 + srow) * BK + scol] = *(const u4v*)(asrc[r] + k0);
#pragma unroll
    for (int r = 0; r < 4; ++r)
      *(u4v*)&Bl[(r * 32 + srow) * BK + scol] = *(const u4v*)(bsrc + (size_t)r * 32 * DIM + k0);
    __syncthreads();
#pragma unroll
    for (int ks = 0; ks < 2; ++ks) {
      s8v af[4], bfr[4];
#pragma unroll
      for (int mt = 0; mt < 4; ++mt)
        af[mt] = __builtin_bit_cast(s8v, *(const u4v*)&Al[(wm * 64 + mt * 16 + lrow) * BK + ks * 32 + lquad * 8]);
#pragma unroll
      for (int nt = 0; nt < 4; ++nt)
        bfr[nt] = __builtin_bit_cast(s8v, *(const u4v*)&Bl[(wn * 64 + nt * 16 + lrow) * BK + ks * 32 + lquad * 8]);
#pragma unroll
      for (int mt = 0; mt < 4; ++mt) {
#pragma unroll
        for (int nt = 0; nt < 4; ++nt)
          acc[mt][nt] = __builtin_amdgcn_mfma_f32_16x16x32_bf16(af[mt], bfr[nt], acc[mt][nt], 0, 0, 0);
      }
    }
    __syncthreads();
  }
  size_t hrow0 = (size_t)blockIdx.x * BM;
#pragma unroll
  for (int nt = 0; nt < 4; ++nt) {
    int gcol = nblock + wn * 64 + nt * 16 + lrow;
    float bias = b1[e * HID + gcol];
#pragma unroll
    for (int mt = 0; mt < 4; ++mt) {
#pragma unroll
      for (int j = 0; j < 4; ++j) {
        int grow = wm * 64 + mt * 16 + lquad * 4 + j;
        float v = acc[mt][nt][j] + bias;
        hbuf[(hrow0 + grow) * HID + gcol] = f2bf(v > 0.f ? v : 0.f);
      }
    }
  }
}

// ---------------- GEMM2: out[tok] += gate * (h @ W2[e] + b2[e]) ----------------
__global__ __launch_bounds__(256) void k_gemm2(const unsigned short* __restrict__ hbuf,
                                               const unsigned short* __restrict__ w2t,
                                               const float* __restrict__ b2,
                                               const int* __restrict__ ptok,
                                               const float* __restrict__ pgate,
                                               const int* __restrict__ meta,
                                               float* __restrict__ out,
                                               int chunk_start) {
  int tile = chunk_start + blockIdx.x;
  if (tile >= meta[0]) return;
  int row0 = tile * BM;
  int e = 0;
#pragma unroll
  for (int i = 1; i < NE; ++i)
    if (row0 >= meta[1 + i]) e = i;
  int nblock = blockIdx.y * BN;
  __shared__ __align__(16) unsigned short Al[BM * BK];
  __shared__ __align__(16) unsigned short Bl[BN * BK];
  int tid = threadIdx.x;
  int lane = tid & 63, w = tid >> 6;
  int wm = w >> 1, wn = w & 1;
  int srow = tid >> 3;
  int scol = (tid & 7) * 8;
  const unsigned short* asrc = hbuf + ((size_t)blockIdx.x * BM + srow) * HID + scol;
  const unsigned short* bsrc = w2t + ((size_t)e * DIM + nblock + srow) * HID + scol;
  f4v acc[4][4] = {};
  int lrow = lane & 15, lquad = lane >> 4;
  for (int k0 = 0; k0 < HID; k0 += BK) {
#pragma unroll
    for (int r = 0; r < 4; ++r)
      *(u4v*)&Al[(r * 32 + srow) * BK + scol] = *(const u4v*)(asrc + (size_t)r * 32 * HID + k0);
#pragma unroll
    for (int r = 0; r < 4; ++r)
      *(u4v*)&Bl[(r * 32 + srow) * BK + scol] = *(const u4v*)(bsrc + (size_t)r * 32 * HID + k0);
    __syncthreads();
#pragma unroll
    for (int ks = 0; ks < 2; ++ks) {
      s8v af[4], bfr[4];
#pragma unroll
      for (int mt = 0; mt < 4; ++mt)
        af[mt] = __builtin_bit_cast(s8v, *(const u4v*)&Al[(wm * 64 + mt * 16 + lrow) * BK + ks * 32 + lquad * 8]);
#pragma unroll
      for (int nt = 0; nt < 4; ++nt)
        bfr[nt] = __builtin_bit_cast(s8v, *(const u4v*)&Bl[(wn * 64 + nt * 16 + lrow) * BK + ks * 32 + lquad * 8]);
#pragma unroll
      for (int mt = 0; mt < 4; ++mt) {
#pragma unroll
        for (int nt = 0; nt < 4; ++nt)
          acc[mt][nt] = __builtin_amdgcn_mfma_f32_16x16x32_bf16(af[mt], bfr[nt], acc[mt][nt], 0, 0, 0);
      }
    }
    __syncthreads();
  }
  float bias[4];
#pragma unroll
  for (int nt = 0; nt < 4; ++nt)
    bias[nt] = b2[e * DIM + nblock + wn * 64 + nt * 16 + lrow];
#pragma unroll
  for (int mt = 0; mt < 4; ++mt) {
#pragma unroll
    for (int j = 0; j < 4; ++j) {
      int p = row0 + wm * 64 + mt * 16 + lquad * 4 + j;
      float g = pgate[p];
      if (g != 0.f) {
        int tok = ptok[p];
        float* orow = out + (size_t)tok * DIM + nblock + wn * 64 + lrow;
#pragma unroll
        for (int nt = 0; nt < 4; ++nt)
          atomicAdd(orow + nt * 16, g * (acc[mt][nt][j] + bias[nt]));
      }
    }
  }
}

extern "C" void kernel_launch(void* const* d_in, const int* in_sizes, int n_in,
                              void* d_out, int out_size, void* d_ws, size_t ws_size,
                              hipStream_t stream) {
  const float* x  = (const float*)d_in[0];
  const float* rw = (const float*)d_in[1];
  const float* rb = (const float*)d_in[2];
  const float* w1 = (const float*)d_in[3];
  const float* b1 = (const float*)d_in[4];
  const float* w2 = (const float*)d_in[5];
  const float* b2 = (const float*)d_in[6];
  float* out = (float*)d_out;
  char* ws = (char*)d_ws;

  size_t o_xb    = 0;
  size_t o_w1t   = o_xb    + (size_t)T_TOK * DIM * 2;
  size_t o_w2t   = o_w1t   + (size_t)NE * DIM * HID * 2;
  size_t o_topki = o_w2t   + (size_t)NE * DIM * HID * 2;
  size_t o_topkg = o_topki + (size_t)T_TOK * TOPK * 4;
  size_t o_meta  = o_topkg + (size_t)T_TOK * TOPK * 4;
  size_t o_ptok  = o_meta  + 16384;
  size_t o_pgate = o_ptok  + (size_t)PAIR_CAP * 4;
  size_t o_h     = o_pgate + (size_t)PAIR_CAP * 4;

  unsigned short* xb   = (unsigned short*)(ws + o_xb);
  unsigned short* w1t  = (unsigned short*)(ws + o_w1t);
  unsigned short* w2t  = (unsigned short*)(ws + o_w2t);
  int*            tki  = (int*)(ws + o_topki);
  float*          tkg  = (float*)(ws + o_topkg);
  int*            meta = (int*)(ws + o_meta);
  int*            ptok = (int*)(ws + o_ptok);
  float*          pgt  = (float*)(ws + o_pgate);
  unsigned short* hbuf = (unsigned short*)(ws + o_h);

  size_t avail = ws_size > o_h ? ws_size - o_h : 0;
  long Cmax = (long)(avail / ((size_t)BM * HID * 2));
  int C = (int)(Cmax < 1 ? 1 : (Cmax > MAX_TILES ? MAX_TILES : Cmax));
  int n_chunks = (MAX_TILES + C - 1) / C;

  hipMemsetAsync(d_out, 0, (size_t)T_TOK * DIM * 4, stream);
  k_cast_x<<<T_TOK * DIM / 1024, 256, 0, stream>>>(x, xb);
  k_transpose_cast<<<dim3(HID / 32, DIM / 32, NE), dim3(32, 8), 0, stream>>>(w1, w1t, DIM, HID);
  k_transpose_cast<<<dim3(DIM / 32, HID / 32, NE), dim3(32, 8), 0, stream>>>(w2, w2t, HID, DIM);
  k_router<<<T_TOK / 4, 256, 0, stream>>>(x, rw, rb, tki, tkg);
  k_count<<<NB_CNT, 256, 0, stream>>>(tki, meta);
  k_plan<<<1, 256, 0, stream>>>(meta, ptok, pgt);
  k_scatter<<<NB_CNT, 256, 0, stream>>>(tki, tkg, meta, ptok, pgt);
  for (int c = 0; c < n_chunks; ++c) {
    k_gemm1<<<dim3(C, HID / BN), 256, 0, stream>>>(xb, w1t, b1, ptok, meta, hbuf, c * C);
    k_gemm2<<<dim3(C, DIM / BN), 256, 0, stream>>>(hbuf, w2t, b2, ptok, pgt, meta, out, c * C);
  }
}

// Round 2
// 831.629 us; speedup vs baseline: 1.0442x; 1.0442x over previous
//
#include <hip/hip_runtime.h>
#include <stdint.h>

#define T_TOK 16384
#define DIM 512
#define HID 2048
#define NE 16
#define TOPK 4
#define BM 128
#define BN 128
#define BK 64
#define PAIR_CAP 67584      // 65536 + 16*128 padding
#define MAX_TILES 528       // PAIR_CAP / BM
#define NB_CNT 64

typedef short s8v __attribute__((ext_vector_type(8)));
typedef float f4v __attribute__((ext_vector_type(4)));
typedef unsigned int u4v __attribute__((ext_vector_type(4)));

__device__ __forceinline__ unsigned short f2bf(float f) {
  unsigned int u = __builtin_bit_cast(unsigned int, f);
  u = (u + 0x7fffu + ((u >> 16) & 1u)) >> 16;
  return (unsigned short)u;
}

// async global->LDS, 16B per lane. LDS dest is wave-uniform base + lane*16.
__device__ __forceinline__ void gload16(const void* g, void* l) {
  __builtin_amdgcn_global_load_lds(
      (const __attribute__((address_space(1))) unsigned int*)(uintptr_t)g,
      (__attribute__((address_space(3))) unsigned int*)(uintptr_t)l,
      16, 0, 0);
}

// ---------------- precast kernels ----------------
__global__ __launch_bounds__(256) void k_cast_x(const float* __restrict__ x,
                                                unsigned short* __restrict__ xb) {
  int i = (blockIdx.x * 256 + threadIdx.x) * 4;
  float4 v = *(const float4*)(x + i);
  ushort4 o;
  o.x = f2bf(v.x); o.y = f2bf(v.y); o.z = f2bf(v.z); o.w = f2bf(v.w);
  *(ushort4*)(xb + i) = o;
}

// src [z][R][C] fp32 -> dst [z][C][R] bf16
__global__ __launch_bounds__(256) void k_transpose_cast(const float* __restrict__ src,
                                                        unsigned short* __restrict__ dst,
                                                        int R, int C) {
  __shared__ float tile[32][33];
  size_t zo = (size_t)blockIdx.z * R * C;
  src += zo; dst += zo;
  int c0 = blockIdx.x * 32, r0 = blockIdx.y * 32;
  int tx = threadIdx.x, ty = threadIdx.y;
#pragma unroll
  for (int i = 0; i < 4; ++i)
    tile[ty + 8 * i][tx] = src[(size_t)(r0 + ty + 8 * i) * C + c0 + tx];
  __syncthreads();
#pragma unroll
  for (int i = 0; i < 4; ++i)
    dst[(size_t)(c0 + ty + 8 * i) * R + r0 + tx] = f2bf(tile[tx][ty + 8 * i]);
}

// ---------------- routing ----------------
__global__ __launch_bounds__(256) void k_router(const float* __restrict__ x,
                                                const float* __restrict__ rw,
                                                const float* __restrict__ rb,
                                                int* __restrict__ topki,
                                                float* __restrict__ topkg) {
  int wv = threadIdx.x >> 6, lane = threadIdx.x & 63;
  int t = blockIdx.x * 4 + wv;
  const float* xr = x + (size_t)t * DIM;
  double acc[NE];
#pragma unroll
  for (int e = 0; e < NE; ++e) acc[e] = 0.0;
  for (int it = 0; it < DIM / 64; ++it) {
    float xv = xr[it * 64 + lane];
    const float* r = rw + (size_t)(it * 64 + lane) * NE;
#pragma unroll
    for (int e = 0; e < NE; ++e) acc[e] += (double)xv * (double)r[e];
  }
#pragma unroll
  for (int off = 32; off >= 1; off >>= 1) {
#pragma unroll
    for (int e = 0; e < NE; ++e) acc[e] += __shfl_xor(acc[e], off, 64);
  }
  if (lane == 0) {
    float v[NE];
#pragma unroll
    for (int e = 0; e < NE; ++e) v[e] = (float)acc[e] + rb[e];
    int idx[TOPK]; float val[TOPK];
#pragma unroll
    for (int k = 0; k < TOPK; ++k) {
      float best = -1e30f; int bi = 0;
#pragma unroll
      for (int e = 0; e < NE; ++e)
        if (v[e] > best) { best = v[e]; bi = e; }
      idx[k] = bi; val[k] = best; v[bi] = -1e30f;
    }
    float m = val[0], s = 0.f, g[TOPK];
#pragma unroll
    for (int k = 0; k < TOPK; ++k) { g[k] = __expf(val[k] - m); s += g[k]; }
    float inv = 1.f / s;
#pragma unroll
    for (int k = 0; k < TOPK; ++k) {
      topki[t * TOPK + k] = idx[k];
      topkg[t * TOPK + k] = g[k] * inv;
    }
  }
}

// meta layout (ints): [0]=tiles_total, [1..17]=padded offsets po[0..16],
// [32..1055]=blockbase[64][16], [1056..2079]=hist[64][16]
__global__ __launch_bounds__(256) void k_count(const int* __restrict__ topki,
                                               int* __restrict__ meta) {
  __shared__ int lcnt[NE];
  int tid = threadIdx.x;
  if (tid < NE) lcnt[tid] = 0;
  __syncthreads();
  int base = blockIdx.x * 1024 + tid * 4;
#pragma unroll
  for (int j = 0; j < 4; ++j) atomicAdd(&lcnt[topki[base + j]], 1);
  __syncthreads();
  if (tid < NE) meta[1056 + blockIdx.x * NE + tid] = lcnt[tid];
}

__global__ __launch_bounds__(256) void k_plan(int* __restrict__ meta,
                                              int* __restrict__ ptok,
                                              float* __restrict__ pgate) {
  __shared__ int cnt_s[NE], po_s[NE + 1];
  int tid = threadIdx.x;
  if (tid < NE) {
    int s = 0;
    for (int b = 0; b < NB_CNT; ++b) s += meta[1056 + b * NE + tid];
    cnt_s[tid] = s;
  }
  __syncthreads();
  if (tid == 0) {
    int off = 0;
    for (int e = 0; e < NE; ++e) {
      po_s[e] = off;
      meta[1 + e] = off;
      off += ((cnt_s[e] + BM - 1) / BM) * BM;
    }
    po_s[NE] = off;
    meta[1 + NE] = off;
    meta[0] = off / BM;
  }
  __syncthreads();
  if (tid < NE) {
    int run = po_s[tid];
    for (int b = 0; b < NB_CNT; ++b) {
      meta[32 + b * NE + tid] = run;
      run += meta[1056 + b * NE + tid];
    }
  }
  for (int e = 0; e < NE; ++e) {
    int start = po_s[e] + cnt_s[e], end = po_s[e + 1];
    for (int i = start + tid; i < end; i += 256) { ptok[i] = 0; pgate[i] = 0.f; }
  }
}

__global__ __launch_bounds__(256) void k_scatter(const int* __restrict__ topki,
                                                 const float* __restrict__ topkg,
                                                 const int* __restrict__ meta,
                                                 int* __restrict__ ptok,
                                                 float* __restrict__ pgate,
                                                 int* __restrict__ sinv) {
  __shared__ int lcnt[NE];
  int tid = threadIdx.x;
  if (tid < NE) lcnt[tid] = 0;
  __syncthreads();
  int base = blockIdx.x * 1024 + tid * 4;
#pragma unroll
  for (int j = 0; j < 4; ++j) {
    int i = base + j;
    int e = topki[i];
    int r = atomicAdd(&lcnt[e], 1);
    int slot = meta[32 + blockIdx.x * NE + e] + r;
    ptok[slot] = i >> 2;
    pgate[slot] = topkg[i];
    sinv[i] = slot;
  }
}

// ---------------- GEMM1: h = relu(X[pairs] @ W1[e] + b1[e]) ----------------
// grid: (HID/BN, C). LDS tiles are XOR-swizzled: phys 16B-group = logical ^ (row&7).
__global__ __launch_bounds__(256) void k_gemm1(const unsigned short* __restrict__ xb,
                                               const unsigned short* __restrict__ w1t,
                                               const float* __restrict__ b1,
                                               const int* __restrict__ ptok,
                                               const int* __restrict__ meta,
                                               unsigned short* __restrict__ hbuf,
                                               int chunk_start) {
  int tile = chunk_start + blockIdx.y;
  if (tile >= meta[0]) return;
  int row0 = tile * BM;
  int e = 0;
#pragma unroll
  for (int i = 1; i < NE; ++i)
    if (row0 >= meta[1 + i]) e = i;
  int nblock = blockIdx.x * BN;
  __shared__ __align__(16) unsigned short Al[BM * BK];
  __shared__ __align__(16) unsigned short Bl[BN * BK];
  int tid = threadIdx.x;
  int lane = tid & 63, w = tid >> 6;
  int wm = w >> 1, wn = w & 1;
  int w4 = w * 4096;
  // staging source setup (lane i handles LDS offset w4 + t*1024 + i*16)
  int sub = lane >> 3;
  int lg = (lane & 7) ^ sub;            // logical k-group fetched by this lane
  const unsigned short* asrc[4];
  const unsigned short* bsrc[4];
#pragma unroll
  for (int t = 0; t < 4; ++t) {
    int r = w * 32 + t * 8 + sub;
    asrc[t] = xb + (size_t)ptok[row0 + r] * DIM + lg * 8;
    bsrc[t] = w1t + ((size_t)e * HID + nblock + r) * DIM + lg * 8;
  }
  f4v acc[4][4] = {};
  int lrow = lane & 15, quad = lane >> 4;
  int r7 = lrow & 7;
  for (int k0 = 0; k0 < DIM; k0 += BK) {
#pragma unroll
    for (int t = 0; t < 4; ++t) gload16(asrc[t] + k0, (char*)Al + w4 + t * 1024);
#pragma unroll
    for (int t = 0; t < 4; ++t) gload16(bsrc[t] + k0, (char*)Bl + w4 + t * 1024);
    __syncthreads();
#pragma unroll
    for (int ks = 0; ks < 2; ++ks) {
      int pg = ((ks * 4 + quad) ^ r7) * 8;
      s8v af[4], bfr[4];
#pragma unroll
      for (int mt = 0; mt < 4; ++mt)
        af[mt] = __builtin_bit_cast(s8v, *(const u4v*)&Al[(wm * 64 + mt * 16 + lrow) * BK + pg]);
#pragma unroll
      for (int nt = 0; nt < 4; ++nt)
        bfr[nt] = __builtin_bit_cast(s8v, *(const u4v*)&Bl[(wn * 64 + nt * 16 + lrow) * BK + pg]);
#pragma unroll
      for (int mt = 0; mt < 4; ++mt) {
#pragma unroll
        for (int nt = 0; nt < 4; ++nt)
          acc[mt][nt] = __builtin_amdgcn_mfma_f32_16x16x32_bf16(af[mt], bfr[nt], acc[mt][nt], 0, 0, 0);
      }
    }
    __syncthreads();
  }
  size_t hrow0 = (size_t)blockIdx.y * BM;
#pragma unroll
  for (int nt = 0; nt < 4; ++nt) {
    int gcol = nblock + wn * 64 + nt * 16 + lrow;
    float bias = b1[e * HID + gcol];
#pragma unroll
    for (int mt = 0; mt < 4; ++mt) {
#pragma unroll
      for (int j = 0; j < 4; ++j) {
        int grow = wm * 64 + mt * 16 + quad * 4 + j;
        float v = acc[mt][nt][j] + bias;
        hbuf[(hrow0 + grow) * HID + gcol] = f2bf(v > 0.f ? v : 0.f);
      }
    }
  }
}

// ---------------- GEMM2: y[slot] = gate*(h @ W2[e] + b2[e]) (or atomic fallback) ---
// grid: (DIM/BN, C)
__global__ __launch_bounds__(256) void k_gemm2(const unsigned short* __restrict__ hbuf,
                                               const unsigned short* __restrict__ w2t,
                                               const float* __restrict__ b2,
                                               const int* __restrict__ ptok,
                                               const float* __restrict__ pgate,
                                               const int* __restrict__ meta,
                                               float* __restrict__ out,
                                               float* __restrict__ yslot,
                                               int chunk_start) {
  int tile = chunk_start + blockIdx.y;
  if (tile >= meta[0]) return;
  int row0 = tile * BM;
  int e = 0;
#pragma unroll
  for (int i = 1; i < NE; ++i)
    if (row0 >= meta[1 + i]) e = i;
  int nblock = blockIdx.x * BN;
  __shared__ __align__(16) unsigned short Al[BM * BK];
  __shared__ __align__(16) unsigned short Bl[BN * BK];
  int tid = threadIdx.x;
  int lane = tid & 63, w = tid >> 6;
  int wm = w >> 1, wn = w & 1;
  int w4 = w * 4096;
  int sub = lane >> 3;
  int lg = (lane & 7) ^ sub;
  const unsigned short* asrc[4];
  const unsigned short* bsrc[4];
#pragma unroll
  for (int t = 0; t < 4; ++t) {
    int r = w * 32 + t * 8 + sub;
    asrc[t] = hbuf + ((size_t)blockIdx.y * BM + r) * HID + lg * 8;
    bsrc[t] = w2t + ((size_t)e * DIM + nblock + r) * HID + lg * 8;
  }
  f4v acc[4][4] = {};
  int lrow = lane & 15, quad = lane >> 4;
  int r7 = lrow & 7;
  for (int k0 = 0; k0 < HID; k0 += BK) {
#pragma unroll
    for (int t = 0; t < 4; ++t) gload16(asrc[t] + k0, (char*)Al + w4 + t * 1024);
#pragma unroll
    for (int t = 0; t < 4; ++t) gload16(bsrc[t] + k0, (char*)Bl + w4 + t * 1024);
    __syncthreads();
#pragma unroll
    for (int ks = 0; ks < 2; ++ks) {
      int pg = ((ks * 4 + quad) ^ r7) * 8;
      s8v af[4], bfr[4];
#pragma unroll
      for (int mt = 0; mt < 4; ++mt)
        af[mt] = __builtin_bit_cast(s8v, *(const u4v*)&Al[(wm * 64 + mt * 16 + lrow) * BK + pg]);
#pragma unroll
      for (int nt = 0; nt < 4; ++nt)
        bfr[nt] = __builtin_bit_cast(s8v, *(const u4v*)&Bl[(wn * 64 + nt * 16 + lrow) * BK + pg]);
#pragma unroll
      for (int mt = 0; mt < 4; ++mt) {
#pragma unroll
        for (int nt = 0; nt < 4; ++nt)
          acc[mt][nt] = __builtin_amdgcn_mfma_f32_16x16x32_bf16(af[mt], bfr[nt], acc[mt][nt], 0, 0, 0);
      }
    }
    __syncthreads();
  }
  float bias[4];
#pragma unroll
  for (int nt = 0; nt < 4; ++nt)
    bias[nt] = b2[e * DIM + nblock + wn * 64 + nt * 16 + lrow];
  if (yslot) {
#pragma unroll
    for (int mt = 0; mt < 4; ++mt) {
#pragma unroll
      for (int j = 0; j < 4; ++j) {
        int p = row0 + wm * 64 + mt * 16 + quad * 4 + j;
        float g = pgate[p];
        float* yr = yslot + (size_t)p * DIM + nblock + wn * 64 + lrow;
#pragma unroll
        for (int nt = 0; nt < 4; ++nt)
          yr[nt * 16] = g * (acc[mt][nt][j] + bias[nt]);
      }
    }
  } else {
#pragma unroll
    for (int mt = 0; mt < 4; ++mt) {
#pragma unroll
      for (int j = 0; j < 4; ++j) {
        int p = row0 + wm * 64 + mt * 16 + quad * 4 + j;
        float g = pgate[p];
        if (g != 0.f) {
          int tok = ptok[p];
          float* orow = out + (size_t)tok * DIM + nblock + wn * 64 + lrow;
#pragma unroll
          for (int nt = 0; nt < 4; ++nt)
            atomicAdd(orow + nt * 16, g * (acc[mt][nt][j] + bias[nt]));
        }
      }
    }
  }
}

// out[t][d] = sum_k yslot[sinv[t*4+k]][d]
__global__ __launch_bounds__(256) void k_gather(const float* __restrict__ yslot,
                                                const int* __restrict__ sinv,
                                                float* __restrict__ out) {
  int id = blockIdx.x * 256 + threadIdx.x;
  int t = id >> 7, d4 = (id & 127) << 2;
  int4 s = *(const int4*)(sinv + t * 4);
  float4 a = *(const float4*)(yslot + (size_t)s.x * DIM + d4);
  float4 b = *(const float4*)(yslot + (size_t)s.y * DIM + d4);
  float4 c = *(const float4*)(yslot + (size_t)s.z * DIM + d4);
  float4 d = *(const float4*)(yslot + (size_t)s.w * DIM + d4);
  float4 r;
  r.x = a.x + b.x + c.x + d.x;
  r.y = a.y + b.y + c.y + d.y;
  r.z = a.z + b.z + c.z + d.z;
  r.w = a.w + b.w + c.w + d.w;
  *(float4*)(out + (size_t)t * DIM + d4) = r;
}

extern "C" void kernel_launch(void* const* d_in, const int* in_sizes, int n_in,
                              void* d_out, int out_size, void* d_ws, size_t ws_size,
                              hipStream_t stream) {
  const float* x  = (const float*)d_in[0];
  const float* rw = (const float*)d_in[1];
  const float* rb = (const float*)d_in[2];
  const float* w1 = (const float*)d_in[3];
  const float* b1 = (const float*)d_in[4];
  const float* w2 = (const float*)d_in[5];
  const float* b2 = (const float*)d_in[6];
  float* out = (float*)d_out;
  char* ws = (char*)d_ws;

  size_t o_xb    = 0;
  size_t o_w1t   = o_xb    + (size_t)T_TOK * DIM * 2;
  size_t o_w2t   = o_w1t   + (size_t)NE * DIM * HID * 2;
  size_t o_topki = o_w2t   + (size_t)NE * DIM * HID * 2;
  size_t o_topkg = o_topki + (size_t)T_TOK * TOPK * 4;
  size_t o_meta  = o_topkg + (size_t)T_TOK * TOPK * 4;
  size_t o_ptok  = o_meta  + 16384;
  size_t o_pgate = o_ptok  + (size_t)PAIR_CAP * 4;
  size_t o_sinv  = o_pgate + (size_t)PAIR_CAP * 4;
  size_t o_yslot = o_sinv  + (size_t)T_TOK * TOPK * 4;
  size_t o_h_slot   = o_yslot + (size_t)PAIR_CAP * DIM * 4;   // slot path
  size_t o_h_atomic = o_yslot;                                 // fallback path

  size_t tile_h = (size_t)BM * HID * 2;
  int use_slot = (ws_size >= o_h_slot + tile_h) ? 1 : 0;
  size_t o_h = use_slot ? o_h_slot : o_h_atomic;

  unsigned short* xb   = (unsigned short*)(ws + o_xb);
  unsigned short* w1t  = (unsigned short*)(ws + o_w1t);
  unsigned short* w2t  = (unsigned short*)(ws + o_w2t);
  int*            tki  = (int*)(ws + o_topki);
  float*          tkg  = (float*)(ws + o_topkg);
  int*            meta = (int*)(ws + o_meta);
  int*            ptok = (int*)(ws + o_ptok);
  float*          pgt  = (float*)(ws + o_pgate);
  int*            sinv = (int*)(ws + o_sinv);
  float*          ysl  = use_slot ? (float*)(ws + o_yslot) : nullptr;
  unsigned short* hbuf = (unsigned short*)(ws + o_h);

  size_t avail = ws_size > o_h ? ws_size - o_h : 0;
  long Cmax = (long)(avail / tile_h);
  int C = (int)(Cmax < 1 ? 1 : (Cmax > MAX_TILES ? MAX_TILES : Cmax));
  int n_chunks = (MAX_TILES + C - 1) / C;

  if (!use_slot) hipMemsetAsync(d_out, 0, (size_t)T_TOK * DIM * 4, stream);
  k_cast_x<<<T_TOK * DIM / 1024, 256, 0, stream>>>(x, xb);
  k_transpose_cast<<<dim3(HID / 32, DIM / 32, NE), dim3(32, 8), 0, stream>>>(w1, w1t, DIM, HID);
  k_transpose_cast<<<dim3(DIM / 32, HID / 32, NE), dim3(32, 8), 0, stream>>>(w2, w2t, HID, DIM);
  k_router<<<T_TOK / 4, 256, 0, stream>>>(x, rw, rb, tki, tkg);
  k_count<<<NB_CNT, 256, 0, stream>>>(tki, meta);
  k_plan<<<1, 256, 0, stream>>>(meta, ptok, pgt);
  k_scatter<<<NB_CNT, 256, 0, stream>>>(tki, tkg, meta, ptok, pgt, sinv);
  for (int c = 0; c < n_chunks; ++c) {
    k_gemm1<<<dim3(HID / BN, C), 256, 0, stream>>>(xb, w1t, b1, ptok, meta, hbuf, c * C);
    k_gemm2<<<dim3(DIM / BN, C), 256, 0, stream>>>(hbuf, w2t, b2, ptok, pgt, meta, out, ysl, c * C);
  }
  if (use_slot)
    k_gather<<<T_TOK * DIM / 4 / 256, 256, 0, stream>>>(ysl, sinv, out);
}

// Round 3
// 725.560 us; speedup vs baseline: 1.1968x; 1.1462x over previous
//
#include <hip/hip_runtime.h>
#include <stdint.h>

#define T_TOK 16384
#define DIM 512
#define HID 2048
#define NE 16
#define TOPK 4
#define BM 128
#define BN 128
#define BK 64
#define PAIR_CAP 67584      // 65536 + 16*128 padding
#define MAX_TILES 528       // PAIR_CAP / BM
#define NB_CNT 64

typedef short s8v __attribute__((ext_vector_type(8)));
typedef float f4v __attribute__((ext_vector_type(4)));
typedef unsigned int u4v __attribute__((ext_vector_type(4)));

__device__ __forceinline__ unsigned short f2bf(float f) {
  unsigned int u = __builtin_bit_cast(unsigned int, f);
  u = (u + 0x7fffu + ((u >> 16) & 1u)) >> 16;
  return (unsigned short)u;
}
__device__ __forceinline__ float bf2f(unsigned short h) {
  return __builtin_bit_cast(float, (unsigned int)h << 16);
}

// async global->LDS, 16B per lane. LDS dest is wave-uniform base + lane*16.
__device__ __forceinline__ void gload16(const void* g, void* l) {
  __builtin_amdgcn_global_load_lds(
      (const __attribute__((address_space(1))) unsigned int*)(uintptr_t)g,
      (__attribute__((address_space(3))) unsigned int*)(uintptr_t)l,
      16, 0, 0);
}

// src [z][R][C] fp32 -> dst [z][C][R] bf16
__global__ __launch_bounds__(256) void k_transpose_cast(const float* __restrict__ src,
                                                        unsigned short* __restrict__ dst,
                                                        int R, int C) {
  __shared__ float tile[32][33];
  size_t zo = (size_t)blockIdx.z * R * C;
  src += zo; dst += zo;
  int c0 = blockIdx.x * 32, r0 = blockIdx.y * 32;
  int tx = threadIdx.x, ty = threadIdx.y;
#pragma unroll
  for (int i = 0; i < 4; ++i)
    tile[ty + 8 * i][tx] = src[(size_t)(r0 + ty + 8 * i) * C + c0 + tx];
  __syncthreads();
#pragma unroll
  for (int i = 0; i < 4; ++i)
    dst[(size_t)(c0 + ty + 8 * i) * R + r0 + tx] = f2bf(tile[tx][ty + 8 * i]);
}

// ---------------- routing (+ fused x->bf16 cast) ----------------
__global__ __launch_bounds__(256) void k_router(const float* __restrict__ x,
                                                const float* __restrict__ rw,
                                                const float* __restrict__ rb,
                                                int* __restrict__ topki,
                                                float* __restrict__ topkg,
                                                unsigned short* __restrict__ xb) {
  int wv = threadIdx.x >> 6, lane = threadIdx.x & 63;
  int t = blockIdx.x * 4 + wv;
  const float* xr = x + (size_t)t * DIM;
  unsigned short* xbr = xb + (size_t)t * DIM;
  double acc[NE];
#pragma unroll
  for (int e = 0; e < NE; ++e) acc[e] = 0.0;
  for (int it = 0; it < DIM / 64; ++it) {
    float xv = xr[it * 64 + lane];
    xbr[it * 64 + lane] = f2bf(xv);
    const float* r = rw + (size_t)(it * 64 + lane) * NE;
#pragma unroll
    for (int e = 0; e < NE; ++e) acc[e] += (double)xv * (double)r[e];
  }
#pragma unroll
  for (int off = 32; off >= 1; off >>= 1) {
#pragma unroll
    for (int e = 0; e < NE; ++e) acc[e] += __shfl_xor(acc[e], off, 64);
  }
  if (lane == 0) {
    float v[NE];
#pragma unroll
    for (int e = 0; e < NE; ++e) v[e] = (float)acc[e] + rb[e];
    int idx[TOPK]; float val[TOPK];
#pragma unroll
    for (int k = 0; k < TOPK; ++k) {
      float best = -1e30f; int bi = 0;
#pragma unroll
      for (int e = 0; e < NE; ++e)
        if (v[e] > best) { best = v[e]; bi = e; }
      idx[k] = bi; val[k] = best; v[bi] = -1e30f;
    }
    float m = val[0], s = 0.f, g[TOPK];
#pragma unroll
    for (int k = 0; k < TOPK; ++k) { g[k] = __expf(val[k] - m); s += g[k]; }
    float inv = 1.f / s;
#pragma unroll
    for (int k = 0; k < TOPK; ++k) {
      topki[t * TOPK + k] = idx[k];
      topkg[t * TOPK + k] = g[k] * inv;
    }
  }
}

// meta layout (ints): [0]=tiles_total, [1..17]=padded offsets po[0..16],
// [32..1055]=blockbase[64][16], [1056..2079]=hist[64][16]
__global__ __launch_bounds__(256) void k_count(const int* __restrict__ topki,
                                               int* __restrict__ meta) {
  __shared__ int lcnt[NE];
  int tid = threadIdx.x;
  if (tid < NE) lcnt[tid] = 0;
  __syncthreads();
  int base = blockIdx.x * 1024 + tid * 4;
#pragma unroll
  for (int j = 0; j < 4; ++j) atomicAdd(&lcnt[topki[base + j]], 1);
  __syncthreads();
  if (tid < NE) meta[1056 + blockIdx.x * NE + tid] = lcnt[tid];
}

__global__ __launch_bounds__(256) void k_plan(int* __restrict__ meta,
                                              int* __restrict__ ptok,
                                              float* __restrict__ pgate) {
  __shared__ int cnt_s[NE], po_s[NE + 1];
  int tid = threadIdx.x;
  if (tid < NE) {
    int s = 0;
    for (int b = 0; b < NB_CNT; ++b) s += meta[1056 + b * NE + tid];
    cnt_s[tid] = s;
  }
  __syncthreads();
  if (tid == 0) {
    int off = 0;
    for (int e = 0; e < NE; ++e) {
      po_s[e] = off;
      meta[1 + e] = off;
      off += ((cnt_s[e] + BM - 1) / BM) * BM;
    }
    po_s[NE] = off;
    meta[1 + NE] = off;
    meta[0] = off / BM;
  }
  __syncthreads();
  if (tid < NE) {
    int run = po_s[tid];
    for (int b = 0; b < NB_CNT; ++b) {
      meta[32 + b * NE + tid] = run;
      run += meta[1056 + b * NE + tid];
    }
  }
  for (int e = 0; e < NE; ++e) {
    int start = po_s[e] + cnt_s[e], end = po_s[e + 1];
    for (int i = start + tid; i < end; i += 256) { ptok[i] = 0; pgate[i] = 0.f; }
  }
}

__global__ __launch_bounds__(256) void k_scatter(const int* __restrict__ topki,
                                                 const float* __restrict__ topkg,
                                                 const int* __restrict__ meta,
                                                 int* __restrict__ ptok,
                                                 float* __restrict__ pgate,
                                                 int* __restrict__ sinv) {
  __shared__ int lcnt[NE];
  int tid = threadIdx.x;
  if (tid < NE) lcnt[tid] = 0;
  __syncthreads();
  int base = blockIdx.x * 1024 + tid * 4;
#pragma unroll
  for (int j = 0; j < 4; ++j) {
    int i = base + j;
    int e = topki[i];
    int r = atomicAdd(&lcnt[e], 1);
    int slot = meta[32 + blockIdx.x * NE + e] + r;
    ptok[slot] = i >> 2;
    pgate[slot] = topkg[i];
    sinv[i] = slot;
  }
}

// ---------------- pipelined combined GEMM dispatch ----------------
// blockIdx.x < 16 : gemm1 role, chunk c1 -> hdst
// blockIdx.x >= 16: gemm2 role, chunk c2 <- hsrc
// LDS tiles XOR-swizzled: phys 16B-group = logical ^ (row&7).
__global__ __launch_bounds__(256) void k_pipe(const unsigned short* __restrict__ xb,
                                              const unsigned short* __restrict__ w1t,
                                              const float* __restrict__ b1,
                                              const unsigned short* __restrict__ w2t,
                                              const float* __restrict__ b2,
                                              const int* __restrict__ ptok,
                                              const float* __restrict__ pgate,
                                              const int* __restrict__ meta,
                                              unsigned short* __restrict__ hdst,
                                              const unsigned short* __restrict__ hsrc,
                                              unsigned short* __restrict__ yslot,
                                              float* __restrict__ out,
                                              int c1, int c2, int C) {
  __shared__ __align__(16) unsigned short Al[BM * BK];
  __shared__ __align__(16) unsigned short Bl[BN * BK];
  int tid = threadIdx.x;
  int lane = tid & 63, w = tid >> 6;
  int wm = w >> 1, wn = w & 1;
  int w4 = w * 4096;
  int sub = lane >> 3;
  int lg = (lane & 7) ^ sub;
  int lrow = lane & 15, quad = lane >> 4;
  int r7 = lrow & 7;

  if (blockIdx.x < 16) {
    // ======== GEMM1: h = relu(X @ W1[e] + b1[e]) ========
    if (c1 < 0) return;
    int tile = c1 * C + blockIdx.y;
    if (tile >= meta[0]) return;
    int row0 = tile * BM;
    int e = 0;
#pragma unroll
    for (int i = 1; i < NE; ++i)
      if (row0 >= meta[1 + i]) e = i;
    int nblock = blockIdx.x * BN;
    const unsigned short* asrc[4];
    const unsigned short* bsrc[4];
#pragma unroll
    for (int t = 0; t < 4; ++t) {
      int r = w * 32 + t * 8 + sub;
      asrc[t] = xb + (size_t)ptok[row0 + r] * DIM + lg * 8;
      bsrc[t] = w1t + ((size_t)e * HID + nblock + r) * DIM + lg * 8;
    }
    f4v acc[4][4] = {};
    for (int k0 = 0; k0 < DIM; k0 += BK) {
#pragma unroll
      for (int t = 0; t < 4; ++t) gload16(asrc[t] + k0, (char*)Al + w4 + t * 1024);
#pragma unroll
      for (int t = 0; t < 4; ++t) gload16(bsrc[t] + k0, (char*)Bl + w4 + t * 1024);
      __syncthreads();
#pragma unroll
      for (int ks = 0; ks < 2; ++ks) {
        int pg = ((ks * 4 + quad) ^ r7) * 8;
        s8v af[4], bfr[4];
#pragma unroll
        for (int mt = 0; mt < 4; ++mt)
          af[mt] = __builtin_bit_cast(s8v, *(const u4v*)&Al[(wm * 64 + mt * 16 + lrow) * BK + pg]);
#pragma unroll
        for (int nt = 0; nt < 4; ++nt)
          bfr[nt] = __builtin_bit_cast(s8v, *(const u4v*)&Bl[(wn * 64 + nt * 16 + lrow) * BK + pg]);
#pragma unroll
        for (int mt = 0; mt < 4; ++mt) {
#pragma unroll
          for (int nt = 0; nt < 4; ++nt)
            acc[mt][nt] = __builtin_amdgcn_mfma_f32_16x16x32_bf16(af[mt], bfr[nt], acc[mt][nt], 0, 0, 0);
        }
      }
      __syncthreads();
    }
    size_t hrow0 = (size_t)blockIdx.y * BM;
#pragma unroll
    for (int nt = 0; nt < 4; ++nt) {
      int gcol = nblock + wn * 64 + nt * 16 + lrow;
      float bias = b1[e * HID + gcol];
#pragma unroll
      for (int mt = 0; mt < 4; ++mt) {
#pragma unroll
        for (int j = 0; j < 4; ++j) {
          int grow = wm * 64 + mt * 16 + quad * 4 + j;
          float v = acc[mt][nt][j] + bias;
          hdst[(hrow0 + grow) * HID + gcol] = f2bf(v > 0.f ? v : 0.f);
        }
      }
    }
  } else {
    // ======== GEMM2: y[slot] = gate*(h @ W2[e] + b2[e]) ========
    if (c2 < 0) return;
    int tile = c2 * C + blockIdx.y;
    if (tile >= meta[0]) return;
    int row0 = tile * BM;
    int e = 0;
#pragma unroll
    for (int i = 1; i < NE; ++i)
      if (row0 >= meta[1 + i]) e = i;
    int nblock = (blockIdx.x - 16) * BN;
    const unsigned short* asrc[4];
    const unsigned short* bsrc[4];
#pragma unroll
    for (int t = 0; t < 4; ++t) {
      int r = w * 32 + t * 8 + sub;
      asrc[t] = hsrc + ((size_t)blockIdx.y * BM + r) * HID + lg * 8;
      bsrc[t] = w2t + ((size_t)e * DIM + nblock + r) * HID + lg * 8;
    }
    f4v acc[4][4] = {};
    for (int k0 = 0; k0 < HID; k0 += BK) {
#pragma unroll
      for (int t = 0; t < 4; ++t) gload16(asrc[t] + k0, (char*)Al + w4 + t * 1024);
#pragma unroll
      for (int t = 0; t < 4; ++t) gload16(bsrc[t] + k0, (char*)Bl + w4 + t * 1024);
      __syncthreads();
#pragma unroll
      for (int ks = 0; ks < 2; ++ks) {
        int pg = ((ks * 4 + quad) ^ r7) * 8;
        s8v af[4], bfr[4];
#pragma unroll
        for (int mt = 0; mt < 4; ++mt)
          af[mt] = __builtin_bit_cast(s8v, *(const u4v*)&Al[(wm * 64 + mt * 16 + lrow) * BK + pg]);
#pragma unroll
        for (int nt = 0; nt < 4; ++nt)
          bfr[nt] = __builtin_bit_cast(s8v, *(const u4v*)&Bl[(wn * 64 + nt * 16 + lrow) * BK + pg]);
#pragma unroll
        for (int mt = 0; mt < 4; ++mt) {
#pragma unroll
          for (int nt = 0; nt < 4; ++nt)
            acc[mt][nt] = __builtin_amdgcn_mfma_f32_16x16x32_bf16(af[mt], bfr[nt], acc[mt][nt], 0, 0, 0);
        }
      }
      __syncthreads();
    }
    float bias[4];
#pragma unroll
    for (int nt = 0; nt < 4; ++nt)
      bias[nt] = b2[e * DIM + nblock + wn * 64 + nt * 16 + lrow];
    if (yslot) {
#pragma unroll
      for (int mt = 0; mt < 4; ++mt) {
#pragma unroll
        for (int j = 0; j < 4; ++j) {
          int p = row0 + wm * 64 + mt * 16 + quad * 4 + j;
          float g = pgate[p];
          unsigned short* yr = yslot + (size_t)p * DIM + nblock + wn * 64 + lrow;
#pragma unroll
          for (int nt = 0; nt < 4; ++nt)
            yr[nt * 16] = f2bf(g * (acc[mt][nt][j] + bias[nt]));
        }
      }
    } else {
#pragma unroll
      for (int mt = 0; mt < 4; ++mt) {
#pragma unroll
        for (int j = 0; j < 4; ++j) {
          int p = row0 + wm * 64 + mt * 16 + quad * 4 + j;
          float g = pgate[p];
          if (g != 0.f) {
            int tok = ptok[p];
            float* orow = out + (size_t)tok * DIM + nblock + wn * 64 + lrow;
#pragma unroll
            for (int nt = 0; nt < 4; ++nt)
              atomicAdd(orow + nt * 16, g * (acc[mt][nt][j] + bias[nt]));
          }
        }
      }
    }
  }
}

// out[t][d] = sum_k yslot[sinv[t*4+k]][d]   (yslot is bf16)
__global__ __launch_bounds__(256) void k_gather(const unsigned short* __restrict__ yslot,
                                                const int* __restrict__ sinv,
                                                float* __restrict__ out) {
  int id = blockIdx.x * 256 + threadIdx.x;
  int t = id >> 7, d4 = (id & 127) << 2;
  int4 s = *(const int4*)(sinv + t * 4);
  int sl[4] = {s.x, s.y, s.z, s.w};
  float sum0 = 0.f, sum1 = 0.f, sum2 = 0.f, sum3 = 0.f;
#pragma unroll
  for (int k = 0; k < 4; ++k) {
    ushort4 v = *(const ushort4*)(yslot + (size_t)sl[k] * DIM + d4);
    sum0 += bf2f(v.x); sum1 += bf2f(v.y); sum2 += bf2f(v.z); sum3 += bf2f(v.w);
  }
  float4 r; r.x = sum0; r.y = sum1; r.z = sum2; r.w = sum3;
  *(float4*)(out + (size_t)t * DIM + d4) = r;
}

extern "C" void kernel_launch(void* const* d_in, const int* in_sizes, int n_in,
                              void* d_out, int out_size, void* d_ws, size_t ws_size,
                              hipStream_t stream) {
  const float* x  = (const float*)d_in[0];
  const float* rw = (const float*)d_in[1];
  const float* rb = (const float*)d_in[2];
  const float* w1 = (const float*)d_in[3];
  const float* b1 = (const float*)d_in[4];
  const float* w2 = (const float*)d_in[5];
  const float* b2 = (const float*)d_in[6];
  float* out = (float*)d_out;
  char* ws = (char*)d_ws;

  size_t o_xb    = 0;
  size_t o_w1t   = o_xb    + (size_t)T_TOK * DIM * 2;
  size_t o_w2t   = o_w1t   + (size_t)NE * DIM * HID * 2;
  size_t o_topki = o_w2t   + (size_t)NE * DIM * HID * 2;
  size_t o_topkg = o_topki + (size_t)T_TOK * TOPK * 4;
  size_t o_meta  = o_topkg + (size_t)T_TOK * TOPK * 4;
  size_t o_ptok  = o_meta  + 16384;
  size_t o_pgate = o_ptok  + (size_t)PAIR_CAP * 4;
  size_t o_sinv  = o_pgate + (size_t)PAIR_CAP * 4;
  size_t o_yslot = o_sinv  + (size_t)T_TOK * TOPK * 4;
  size_t o_hb    = o_yslot + (size_t)PAIR_CAP * DIM * 2;   // bf16 yslot

  unsigned short* xb   = (unsigned short*)(ws + o_xb);
  unsigned short* w1t  = (unsigned short*)(ws + o_w1t);
  unsigned short* w2t  = (unsigned short*)(ws + o_w2t);
  int*            tki  = (int*)(ws + o_topki);
  float*          tkg  = (float*)(ws + o_topkg);
  int*            meta = (int*)(ws + o_meta);
  int*            ptok = (int*)(ws + o_ptok);
  float*          pgt  = (float*)(ws + o_pgate);
  int*            sinv = (int*)(ws + o_sinv);

  size_t tile_h = (size_t)BM * HID * 2;
  size_t avail = ws_size > o_hb ? ws_size - o_hb : 0;
  long Cd = (long)(avail / (2 * tile_h));
  int use_slot = Cd >= 1;

  k_router<<<T_TOK / 4, 256, 0, stream>>>(x, rw, rb, tki, tkg, xb);
  k_transpose_cast<<<dim3(HID / 32, DIM / 32, NE), dim3(32, 8), 0, stream>>>(w1, w1t, DIM, HID);
  k_transpose_cast<<<dim3(DIM / 32, HID / 32, NE), dim3(32, 8), 0, stream>>>(w2, w2t, HID, DIM);
  k_count<<<NB_CNT, 256, 0, stream>>>(tki, meta);
  k_plan<<<1, 256, 0, stream>>>(meta, ptok, pgt);
  k_scatter<<<NB_CNT, 256, 0, stream>>>(tki, tkg, meta, ptok, pgt, sinv);

  if (use_slot) {
    unsigned short* ysl = (unsigned short*)(ws + o_yslot);
    int C = (int)(Cd > MAX_TILES ? MAX_TILES : Cd);
    int n_chunks = (MAX_TILES + C - 1) / C;
    unsigned short* hb0 = (unsigned short*)(ws + o_hb);
    unsigned short* hb1 = hb0 + (size_t)C * BM * HID;
    for (int i = 0; i <= n_chunks; ++i) {
      unsigned short* dst = (i & 1) ? hb1 : hb0;
      unsigned short* src = (i & 1) ? hb0 : hb1;
      int c1 = (i < n_chunks) ? i : -1;
      int c2 = i - 1;
      k_pipe<<<dim3(20, C), 256, 0, stream>>>(xb, w1t, b1, w2t, b2, ptok, pgt, meta,
                                              dst, src, ysl, out, c1, c2, C);
    }
    k_gather<<<T_TOK * DIM / 4 / 256, 256, 0, stream>>>(ysl, sinv, out);
  } else {
    // fallback: single hbuf at o_yslot, serial role launches, atomic epilogue
    long Cf = (long)((ws_size - o_yslot) / tile_h);
    int C = (int)(Cf < 1 ? 1 : (Cf > MAX_TILES ? MAX_TILES : Cf));
    int n_chunks = (MAX_TILES + C - 1) / C;
    unsigned short* hb = (unsigned short*)(ws + o_yslot);
    hipMemsetAsync(d_out, 0, (size_t)T_TOK * DIM * 4, stream);
    for (int i = 0; i < n_chunks; ++i) {
      k_pipe<<<dim3(20, C), 256, 0, stream>>>(xb, w1t, b1, w2t, b2, ptok, pgt, meta,
                                              hb, hb, nullptr, out, i, -1, C);
      k_pipe<<<dim3(20, C), 256, 0, stream>>>(xb, w1t, b1, w2t, b2, ptok, pgt, meta,
                                              hb, hb, nullptr, out, -1, i, C);
    }
  }
}